// Round 15
// baseline (159.818 us; speedup 1.0000x reference)
//
#include <hip/hip_runtime.h>
#include <hip/hip_bf16.h>

#define BATCH 16384
#define MAX_ITEMS 200
#define TOTAL (BATCH * MAX_ITEMS)
#define NUM_ITEMS 100000
#define PACK_BLOCKS ((NUM_ITEMS + 255) / 256)   // 391

typedef _Float16 half8 __attribute__((ext_vector_type(8)));
typedef float    f32x4 __attribute__((ext_vector_type(4)));
typedef int      i32x4 __attribute__((ext_vector_type(4)));

// ---------------------------------------------------------------------------
// Kernel PACK: packed[i] = {gmf_emb[i][0..3], ncf_emb[i][0..3]} as 8 x f16.
// One 16B row per item -> one gather per item in the score kernel.
// ---------------------------------------------------------------------------
__global__ __launch_bounds__(256) void pack_items(
    const float* __restrict__ gmf_emb,
    const float* __restrict__ ncf_emb,
    half8* __restrict__ packed)
{
    int i = blockIdx.x * 256 + threadIdx.x;
    if (i >= NUM_ITEMS) return;
    float4 g = reinterpret_cast<const float4*>(gmf_emb)[i];
    float4 c = reinterpret_cast<const float4*>(ncf_emb)[i];
    half8 z;
    z[0] = (_Float16)g.x; z[1] = (_Float16)g.y;
    z[2] = (_Float16)g.z; z[3] = (_Float16)g.w;
    z[4] = (_Float16)c.x; z[5] = (_Float16)c.y;
    z[6] = (_Float16)c.z; z[7] = (_Float16)c.w;
    packed[i] = z;
}

// ---------------------------------------------------------------------------
// Kernel SCORE_FUSED: one block = 4 users = 800 items. 4096 blocks.
//  ph0: issue nt ratings/ids loads (tid<200, 4 items each)
//  ph1: stage 4 users' uemb+noise rows to LDS (coalesced) + small tables
//  ph2: 16 projections (64->4) computed in-block:
//       2a: 64 threads do quarter-dots (len 16)   2b: combine+bias
//       2c: fold to 12 per-user consts (uu[4], base[8]) in LDS
//  ph3: tid<200 scores 4 items: ONE nt 16B gather per item (L1 bypass
//       theory: gathers always miss L1; nt avoids L1 allocation/miss-handling)
// Weights W0..W3 are read per-block but are 4KB total -> L1/L2 resident.
// ---------------------------------------------------------------------------
__global__ __launch_bounds__(256) void score_fused(
    const float* __restrict__ ratings,
    const int*   __restrict__ ids,
    const half8* __restrict__ packed,
    const float* __restrict__ noise,
    const float* __restrict__ uemb,
    const float* __restrict__ W0, const float* __restrict__ b0,
    const float* __restrict__ W1, const float* __restrict__ b1,
    const float* __restrict__ W2, const float* __restrict__ b2,
    const float* __restrict__ W3, const float* __restrict__ b3,
    const float* __restrict__ Wn, const float* __restrict__ bn,
    const float* __restrict__ Wf, const float* __restrict__ bf,
    const float* __restrict__ p,
    float* __restrict__ out)
{
    __shared__ float sIn[4 * 264];    // [u][0:128]=uemb row, [128:256]=noise row
    __shared__ float sPart[4 * 4 * 16];
    __shared__ float sproj[4 * 17];
    __shared__ float sConsts[4 * 12]; // per user: uu[4], base[8]
    __shared__ float sWn[32];         // Wn[k][8+i], k-major
    __shared__ float sWf[8];          // Wf[8+k]
    __shared__ float sBF, sP;

    const int tid = threadIdx.x;
    const int ub  = blockIdx.x * 4;

    // ---- phase 0: issue streaming loads (latency hides under ph1/ph2) ----
    f32x4 r4 = {0.f, 0.f, 0.f, 0.f};
    i32x4 id4 = {0, 0, 0, 0};
    const int t = blockIdx.x * 200 + tid;          // float4/int4 index
    if (tid < 200) {
        r4  = __builtin_nontemporal_load(reinterpret_cast<const f32x4*>(ratings) + t);
        id4 = __builtin_nontemporal_load(reinterpret_cast<const i32x4*>(ids) + t);
    }

    // ---- phase 1: stage rows + small tables ----
    if (tid < 128) {
        int u_l = tid >> 5, seg = tid & 31;
        float4 v = reinterpret_cast<const float4*>(uemb + (size_t)ub * 128)[tid];
        *reinterpret_cast<float4*>(&sIn[u_l * 264 + seg * 4]) = v;
    } else {
        int k = tid - 128;
        int u_l = k >> 5, seg = k & 31;
        float4 v = reinterpret_cast<const float4*>(noise + (size_t)ub * 128)[k];
        *reinterpret_cast<float4*>(&sIn[u_l * 264 + 128 + seg * 4]) = v;
    }
    if (tid < 32)       sWn[tid] = Wn[(tid >> 2) * 12 + 8 + (tid & 3)];
    else if (tid < 40)  sWf[tid - 32] = Wf[8 + (tid - 32)];
    else if (tid == 40) sBF = bf[0];
    else if (tid == 41) sP  = p[0];
    __syncthreads();

    // ---- phase 2a: quarter-dots. thread (u_l, r, q), 64 active ----
    if (tid < 64) {
        int u_l = tid >> 4, r = (tid >> 2) & 3, q = tid & 3;
        const float* Wr = (r == 0) ? W0 : (r == 1) ? W1 : (r == 2) ? W2 : W3;
        const float4* x4 = reinterpret_cast<const float4*>(&sIn[u_l * 264 + r * 64 + q * 16]);
        float s0 = 0.f, s1 = 0.f, s2 = 0.f, s3 = 0.f;
#pragma unroll
        for (int i4 = 0; i4 < 4; ++i4) {
            float4 x  = x4[i4];
            float4 w0 = reinterpret_cast<const float4*>(Wr + 0 * 64 + q * 16)[i4];
            float4 w1 = reinterpret_cast<const float4*>(Wr + 1 * 64 + q * 16)[i4];
            float4 w2 = reinterpret_cast<const float4*>(Wr + 2 * 64 + q * 16)[i4];
            float4 w3 = reinterpret_cast<const float4*>(Wr + 3 * 64 + q * 16)[i4];
            s0 += x.x * w0.x + x.y * w0.y + x.z * w0.z + x.w * w0.w;
            s1 += x.x * w1.x + x.y * w1.y + x.z * w1.z + x.w * w1.w;
            s2 += x.x * w2.x + x.y * w2.y + x.z * w2.z + x.w * w2.w;
            s3 += x.x * w3.x + x.y * w3.y + x.z * w3.z + x.w * w3.w;
        }
        int b = (u_l * 4 + r) * 16;
        sPart[b + 0 * 4 + q] = s0;
        sPart[b + 1 * 4 + q] = s1;
        sPart[b + 2 * 4 + q] = s2;
        sPart[b + 3 * 4 + q] = s3;
    }
    __syncthreads();

    // ---- phase 2b: combine quarters + bias. thread (u_l, r, j) ----
    if (tid < 64) {
        int u_l = tid >> 4, r = (tid >> 2) & 3, j = tid & 3;
        const float* br = (r == 0) ? b0 : (r == 1) ? b1 : (r == 2) ? b2 : b3;
        int b = (u_l * 4 + r) * 16 + j * 4;
        sproj[u_l * 17 + r * 4 + j] =
            sPart[b + 0] + sPart[b + 1] + sPart[b + 2] + sPart[b + 3] + br[j];
    }
    __syncthreads();

    // ---- phase 2c: fold to 12 consts per user. thread = user ----
    if (tid < 4) {
        float pr[16];
#pragma unroll
        for (int c = 0; c < 16; ++c) pr[c] = sproj[tid * 17 + c];
        // pr[0..3]=gmf_user, [4..7]=ncf_user, [8..11]=gmf_noise, [12..15]=ncf_noise
        float* o = &sConsts[tid * 12];
#pragma unroll
        for (int j = 0; j < 4; ++j)
            o[j] = Wf[j] * pr[j] + Wf[4 + j] * pr[8 + j];
#pragma unroll
        for (int k = 0; k < 8; ++k) {
            float s = bn[k];
#pragma unroll
            for (int i = 0; i < 4; ++i)
                s += Wn[k * 12 + i] * pr[4 + i] + Wn[k * 12 + 4 + i] * pr[12 + i];
            o[4 + k] = s;
        }
    }
    __syncthreads();

    // ---- phase 3: score 4 items/thread ----
    if (tid < 200) {
        const int u_l = tid / 50;                 // magic mul
        const float* cw = &sConsts[u_l * 12];
        const float c0x = cw[0], c0y = cw[1], c0z = cw[2], c0w = cw[3];
        float base[8];
#pragma unroll
        for (int k = 0; k < 8; ++k) base[k] = cw[4 + k];

        const i32x4* ptab = reinterpret_cast<const i32x4*>(packed);
        i32x4 zz0 = __builtin_nontemporal_load(ptab + id4.x);
        i32x4 zz1 = __builtin_nontemporal_load(ptab + id4.y);
        i32x4 zz2 = __builtin_nontemporal_load(ptab + id4.z);
        i32x4 zz3 = __builtin_nontemporal_load(ptab + id4.w);
        half8 z0 = __builtin_bit_cast(half8, zz0);
        half8 z1 = __builtin_bit_cast(half8, zz1);
        half8 z2 = __builtin_bit_cast(half8, zz2);
        half8 z3 = __builtin_bit_cast(half8, zz3);

        const half8 zs[4] = {z0, z1, z2, z3};
        const float rr[4] = {r4.x, r4.y, r4.z, r4.w};
        float res[4];
#pragma unroll
        for (int e = 0; e < 4; ++e) {
            half8 z = zs[e];
            float gx = (float)z[0], gy = (float)z[1], gz = (float)z[2], gw = (float)z[3];
            float nx = (float)z[4], ny = (float)z[5], nz = (float)z[6], nw = (float)z[7];
            float acc = sBF + gx * c0x + gy * c0y + gz * c0z + gw * c0w;
#pragma unroll
            for (int k = 0; k < 8; ++k) {
                float tv = base[k]
                         + sWn[k * 4 + 0] * nx
                         + sWn[k * 4 + 1] * ny
                         + sWn[k * 4 + 2] * nz
                         + sWn[k * 4 + 3] * nw;
                acc += sWf[k] * fmaxf(tv, 0.0f);
            }
            res[e] = sP * rr[e] + acc;
        }

        f32x4 o4;
        o4.x = res[0]; o4.y = res[1]; o4.z = res[2]; o4.w = res[3];
        __builtin_nontemporal_store(o4, reinterpret_cast<f32x4*>(out) + t);
    }
}

extern "C" void kernel_launch(void* const* d_in, const int* in_sizes, int n_in,
                              void* d_out, int out_size, void* d_ws, size_t ws_size,
                              hipStream_t stream) {
    const float* ratings = (const float*)d_in[0];
    const int*   ids     = (const int*)  d_in[1];
    const float* noise   = (const float*)d_in[2];
    const float* uemb    = (const float*)d_in[3];
    const float* gmf_emb = (const float*)d_in[4];
    const float* ncf_emb = (const float*)d_in[5];
    const float* W0 = (const float*)d_in[6];
    const float* b0 = (const float*)d_in[7];
    const float* W1 = (const float*)d_in[8];
    const float* b1 = (const float*)d_in[9];
    const float* W2 = (const float*)d_in[10];
    const float* b2 = (const float*)d_in[11];
    const float* W3 = (const float*)d_in[12];
    const float* b3 = (const float*)d_in[13];
    const float* Wn = (const float*)d_in[14];
    const float* bn = (const float*)d_in[15];
    const float* Wf = (const float*)d_in[16];
    const float* bf = (const float*)d_in[17];
    const float* p  = (const float*)d_in[18];
    float* out = (float*)d_out;

    half8* packed = (half8*)d_ws;   // 100000 * 16B = 1.6 MB

    pack_items<<<PACK_BLOCKS, 256, 0, stream>>>(gmf_emb, ncf_emb, packed);

    score_fused<<<BATCH / 4, 256, 0, stream>>>(
        ratings, ids, packed, noise, uemb,
        W0, b0, W1, b1, W2, b2, W3, b3, Wn, bn, Wf, bf, p, out);
}

// Round 18
// 141.911 us; speedup vs baseline: 1.1262x; 1.1262x over previous
//
#include <hip/hip_runtime.h>
#include <hip/hip_bf16.h>

#define BATCH 16384
#define MAX_ITEMS 200
#define TOTAL (BATCH * MAX_ITEMS)
#define NUM_ITEMS 100000
#define A_USERS 64
#define PREP_A_BLOCKS (BATCH / A_USERS)                    // 256
#define PACK_BLOCKS ((NUM_ITEMS + 255) / 256)              // 391

typedef _Float16 half8 __attribute__((ext_vector_type(8)));
typedef float    f32x4 __attribute__((ext_vector_type(4)));
typedef int      i32x4 __attribute__((ext_vector_type(4)));

// ---------------------------------------------------------------------------
// Kernel PREP (merged): blocks [0,256) do per-user constants; blocks
// [256, 256+391) pack the item tables into one 16B f16 row each:
//   packed[i] = {gmf_emb[i][0..3], ncf_emb[i][0..3]}
// ---------------------------------------------------------------------------
__global__ __launch_bounds__(256) void prep(
    const float* __restrict__ noise,
    const float* __restrict__ uemb,
    const float* __restrict__ gmf_emb,
    const float* __restrict__ ncf_emb,
    const float* __restrict__ W0, const float* __restrict__ b0,
    const float* __restrict__ W1, const float* __restrict__ b1,
    const float* __restrict__ W2, const float* __restrict__ b2,
    const float* __restrict__ W3, const float* __restrict__ b3,
    const float* __restrict__ Wn, const float* __restrict__ bn,
    const float* __restrict__ Wf,
    float* __restrict__ consts,
    half8* __restrict__ packed)
{
    const int tid = threadIdx.x;

    if (blockIdx.x >= PREP_A_BLOCKS) {
        // ---- pack path ----
        int i = (blockIdx.x - PREP_A_BLOCKS) * 256 + tid;
        if (i < NUM_ITEMS) {
            float4 g = reinterpret_cast<const float4*>(gmf_emb)[i];
            float4 c = reinterpret_cast<const float4*>(ncf_emb)[i];
            half8 z;
            z[0] = (_Float16)g.x; z[1] = (_Float16)g.y;
            z[2] = (_Float16)g.z; z[3] = (_Float16)g.w;
            z[4] = (_Float16)c.x; z[5] = (_Float16)c.y;
            z[6] = (_Float16)c.z; z[7] = (_Float16)c.w;
            packed[i] = z;
        }
        return;
    }

    // ---- per-user constants path ----
    __shared__ float sIn[A_USERS * 260];   // [u][0:128]=uemb row, [128:256]=noise row
    __shared__ float sW[16 * 68];          // rows r*4+j, stride 68
    __shared__ float sproj[A_USERS * 17];

    const int ub = blockIdx.x * A_USERS;

    for (int k = tid; k < 1024; k += 256) {
        int row = k >> 6, i = k & 63;
        int r = row >> 2, j = row & 3;
        const float* Wr = (r == 0) ? W0 : (r == 1) ? W1 : (r == 2) ? W2 : W3;
        sW[row * 68 + i] = Wr[j * 64 + i];
    }

    const float4* ue4 = reinterpret_cast<const float4*>(uemb  + (size_t)ub * 128);
    const float4* no4 = reinterpret_cast<const float4*>(noise + (size_t)ub * 128);
#pragma unroll
    for (int it = 0; it < 8; ++it) {
        int k   = it * 256 + tid;          // 0 .. 2047
        int u_l = k >> 5, seg = k & 31;
        float4 v = ue4[k];
        float4 w = no4[k];
        *reinterpret_cast<float4*>(&sIn[u_l * 260 + seg * 4])       = v;
        *reinterpret_cast<float4*>(&sIn[u_l * 260 + 128 + seg * 4]) = w;
    }
    __syncthreads();

    const int u_local = tid >> 2;
    const int r       = tid & 3;
    const float4* src = reinterpret_cast<const float4*>(&sIn[u_local * 260 + r * 64]);
    const float4* w0p = reinterpret_cast<const float4*>(&sW[(r * 4 + 0) * 68]);
    const float4* w1p = reinterpret_cast<const float4*>(&sW[(r * 4 + 1) * 68]);
    const float4* w2p = reinterpret_cast<const float4*>(&sW[(r * 4 + 2) * 68]);
    const float4* w3p = reinterpret_cast<const float4*>(&sW[(r * 4 + 3) * 68]);

    float a0 = 0.f, a1 = 0.f, a2 = 0.f, a3 = 0.f;
#pragma unroll
    for (int i4 = 0; i4 < 16; ++i4) {
        float4 x  = src[i4];
        float4 w0 = w0p[i4];
        float4 w1 = w1p[i4];
        float4 w2 = w2p[i4];
        float4 w3 = w3p[i4];
        a0 += x.x * w0.x + x.y * w0.y + x.z * w0.z + x.w * w0.w;
        a1 += x.x * w1.x + x.y * w1.y + x.z * w1.z + x.w * w1.w;
        a2 += x.x * w2.x + x.y * w2.y + x.z * w2.z + x.w * w2.w;
        a3 += x.x * w3.x + x.y * w3.y + x.z * w3.z + x.w * w3.w;
    }
    const float* br = (r == 0) ? b0 : (r == 1) ? b1 : (r == 2) ? b2 : b3;
    sproj[u_local * 17 + r * 4 + 0] = a0 + br[0];
    sproj[u_local * 17 + r * 4 + 1] = a1 + br[1];
    sproj[u_local * 17 + r * 4 + 2] = a2 + br[2];
    sproj[u_local * 17 + r * 4 + 3] = a3 + br[3];
    __syncthreads();

    if (tid < A_USERS) {
        float pr[16];
#pragma unroll
        for (int c = 0; c < 16; ++c) pr[c] = sproj[tid * 17 + c];
        // pr[0..3]=gmf_user, [4..7]=ncf_user, [8..11]=gmf_noise, [12..15]=ncf_noise

        float uu[4], base[8];
#pragma unroll
        for (int j = 0; j < 4; ++j)
            uu[j] = Wf[j] * pr[j] + Wf[4 + j] * pr[8 + j];
#pragma unroll
        for (int k = 0; k < 8; ++k) {
            float t = bn[k];
#pragma unroll
            for (int i = 0; i < 4; ++i)
                t += Wn[k * 12 + i] * pr[4 + i] + Wn[k * 12 + 4 + i] * pr[12 + i];
            base[k] = t;
        }
        float4* o = reinterpret_cast<float4*>(consts + (size_t)(ub + tid) * 12);
        o[0] = make_float4(uu[0], uu[1], uu[2], uu[3]);
        o[1] = make_float4(base[0], base[1], base[2], base[3]);
        o[2] = make_float4(base[4], base[5], base[6], base[7]);
    }
}

// ---------------------------------------------------------------------------
// Kernel B: scoring, 4 items per thread, ONE 16B gather per item.
// Streams (ratings/ids/out): non-temporal (nt) — proven ~neutral-positive.
// Gathers: sc0 (L1-bypass, L2-ALLOCATE) via inline asm. Theory: gathers
// always miss L1 (random over 1.6MB table vs 32KB L1) and each miss pins an
// L1 miss-slot for a ~200cy L2 round trip -> MSHR-occupancy-limited. sc0
// routes around L1 allocation while keeping the table L2-resident (unlike
// R15's nt-gathers, which bypassed L2 too: FETCH 28->62.8MB, -20us).
// The s_waitcnt lives INSIDE the asm block that defines the outputs, so
// consumers cannot be scheduled before the wait (rule-#18-safe).
// ---------------------------------------------------------------------------
__global__ __launch_bounds__(256) void score4(
    const float* __restrict__ ratings,
    const int*   __restrict__ ids,
    const half8* __restrict__ packed,
    const float* __restrict__ Wn,
    const float* __restrict__ Wf,
    const float* __restrict__ bf,
    const float* __restrict__ p,
    const float* __restrict__ consts,
    float* __restrict__ out)
{
    __shared__ float sWn[32];  // Wn[k][8+i], k-major
    __shared__ float sWf[8];   // Wf[8+k]
    __shared__ float sBF, sP;

    const int tid = threadIdx.x;
    if (tid < 32)       sWn[tid] = Wn[(tid >> 2) * 12 + 8 + (tid & 3)];
    else if (tid < 40)  sWf[tid - 32] = Wf[8 + (tid - 32)];
    else if (tid == 40) sBF = bf[0];
    else if (tid == 41) sP  = p[0];
    __syncthreads();

    const int t = blockIdx.x * 256 + tid;          // 0 .. 204799
    const int u = t / (MAX_ITEMS / 4);             // t / 50 -> magic mul

    f32x4 r4  = __builtin_nontemporal_load(reinterpret_cast<const f32x4*>(ratings) + t);
    i32x4 id4 = __builtin_nontemporal_load(reinterpret_cast<const i32x4*>(ids) + t);

    // 4 independent 16B gathers, L1-bypass (sc0), L2-cached.
    const half8* a0 = packed + id4.x;
    const half8* a1 = packed + id4.y;
    const half8* a2 = packed + id4.z;
    const half8* a3 = packed + id4.w;
    i32x4 zz0, zz1, zz2, zz3;
    asm volatile(
        "global_load_dwordx4 %0, %4, off sc0\n\t"
        "global_load_dwordx4 %1, %5, off sc0\n\t"
        "global_load_dwordx4 %2, %6, off sc0\n\t"
        "global_load_dwordx4 %3, %7, off sc0\n\t"
        "s_waitcnt vmcnt(0)"
        : "=&v"(zz0), "=&v"(zz1), "=&v"(zz2), "=&v"(zz3)
        : "v"(a0), "v"(a1), "v"(a2), "v"(a3)
        : "memory");
    half8 z0 = __builtin_bit_cast(half8, zz0);
    half8 z1 = __builtin_bit_cast(half8, zz1);
    half8 z2 = __builtin_bit_cast(half8, zz2);
    half8 z3 = __builtin_bit_cast(half8, zz3);

    const float4* cu = reinterpret_cast<const float4*>(consts + (size_t)u * 12);
    float4 c0 = cu[0];   // uu
    float4 c1 = cu[1];   // base[0..3]
    float4 c2 = cu[2];   // base[4..7]
    const float base[8] = {c1.x, c1.y, c1.z, c1.w, c2.x, c2.y, c2.z, c2.w};

    const half8 zs[4] = {z0, z1, z2, z3};
    const float rr[4] = {r4.x, r4.y, r4.z, r4.w};
    float res[4];

#pragma unroll
    for (int e = 0; e < 4; ++e) {
        half8 z = zs[e];
        float gx = (float)z[0], gy = (float)z[1], gz = (float)z[2], gw = (float)z[3];
        float nx = (float)z[4], ny = (float)z[5], nz = (float)z[6], nw = (float)z[7];
        float acc = sBF + gx * c0.x + gy * c0.y + gz * c0.z + gw * c0.w;
#pragma unroll
        for (int k = 0; k < 8; ++k) {
            float tv = base[k]
                     + sWn[k * 4 + 0] * nx
                     + sWn[k * 4 + 1] * ny
                     + sWn[k * 4 + 2] * nz
                     + sWn[k * 4 + 3] * nw;
            acc += sWf[k] * fmaxf(tv, 0.0f);
        }
        res[e] = sP * rr[e] + acc;
    }

    f32x4 o4;
    o4.x = res[0]; o4.y = res[1]; o4.z = res[2]; o4.w = res[3];
    __builtin_nontemporal_store(o4, reinterpret_cast<f32x4*>(out) + t);
}

extern "C" void kernel_launch(void* const* d_in, const int* in_sizes, int n_in,
                              void* d_out, int out_size, void* d_ws, size_t ws_size,
                              hipStream_t stream) {
    const float* ratings = (const float*)d_in[0];
    const int*   ids     = (const int*)  d_in[1];
    const float* noise   = (const float*)d_in[2];
    const float* uemb    = (const float*)d_in[3];
    const float* gmf_emb = (const float*)d_in[4];
    const float* ncf_emb = (const float*)d_in[5];
    const float* W0 = (const float*)d_in[6];
    const float* b0 = (const float*)d_in[7];
    const float* W1 = (const float*)d_in[8];
    const float* b1 = (const float*)d_in[9];
    const float* W2 = (const float*)d_in[10];
    const float* b2 = (const float*)d_in[11];
    const float* W3 = (const float*)d_in[12];
    const float* b3 = (const float*)d_in[13];
    const float* Wn = (const float*)d_in[14];
    const float* bn = (const float*)d_in[15];
    const float* Wf = (const float*)d_in[16];
    const float* bf = (const float*)d_in[17];
    const float* p  = (const float*)d_in[18];
    float* out = (float*)d_out;

    // ws layout: [0, 1.6MB) packed f16 item table; [2MB, 2MB+768KB) user consts
    half8* packed = (half8*)d_ws;
    float* consts = (float*)((char*)d_ws + (1u << 21));

    prep<<<PREP_A_BLOCKS + PACK_BLOCKS, 256, 0, stream>>>(
        noise, uemb, gmf_emb, ncf_emb,
        W0, b0, W1, b1, W2, b2, W3, b3, Wn, bn, Wf, consts, packed);

    score4<<<TOTAL / 4 / 256, 256, 0, stream>>>(
        ratings, ids, packed, Wn, Wf, bf, p, consts, out);
}